// Round 7
// baseline (1546.330 us; speedup 1.0000x reference)
//
#include <hip/hip_runtime.h>

#define D_EMB   64
#define D_HID   128
#define NUM_EL  118
#define CHUNK   1024
#define NBINS   16
#define MAGIC   0x51A7F00Du
#define MAGIC2  0xC0FFEE11u
#define CLIMIT  4000      // consumer poll bound (~ms scale) before self-compute
#define ALIMIT  4000      // aggregator poll bound

// ---------------------------------------------------------------------------
// Block-cooperative 2-layer MLP for one element zz. All 256 threads must call
// (contains __syncthreads). Returns E (valid in all threads).
// ---------------------------------------------------------------------------
__device__ __forceinline__ float mlp_E(int zz, int t,
        const float* __restrict__ embed,
        const float* __restrict__ W1, const float* __restrict__ b1,
        const float* __restrict__ W2, const float* __restrict__ b2,
        const float* __restrict__ W3, const float* __restrict__ b3,
        float* h, float* x1, float* part, float* wsum) {
    const int j  = t & 127;
    const int hf = t >> 7;

    if (t < D_EMB) h[t] = embed[zz * D_EMB + t];
    __syncthreads();

    // layer 1: k-range split 32/32 across hf
    {
        const int k0 = hf * 32;
        float a0 = 0.f, a1 = 0.f, a2 = 0.f, a3 = 0.f;
        #pragma unroll
        for (int k = 0; k < 32; k += 4) {
            a0 = fmaf(h[k0 + k + 0], W1[(k0 + k + 0) * D_HID + j], a0);
            a1 = fmaf(h[k0 + k + 1], W1[(k0 + k + 1) * D_HID + j], a1);
            a2 = fmaf(h[k0 + k + 2], W1[(k0 + k + 2) * D_HID + j], a2);
            a3 = fmaf(h[k0 + k + 3], W1[(k0 + k + 3) * D_HID + j], a3);
        }
        const float p = (a0 + a1) + (a2 + a3);
        if (hf == 1) part[j] = p;
        __syncthreads();
        if (hf == 0) {
            const float acc = b1[j] + p + part[j];
            x1[j] = acc / (1.0f + expf(-acc));
        }
        __syncthreads();
    }

    // layer 2 + dot(W3): k-range split 64/64 across hf
    float r = 0.f;
    {
        const int k0 = hf * 64;
        float a0 = 0.f, a1 = 0.f, a2 = 0.f, a3 = 0.f;
        #pragma unroll
        for (int k = 0; k < 64; k += 4) {
            a0 = fmaf(x1[k0 + k + 0], W2[(k0 + k + 0) * D_HID + j], a0);
            a1 = fmaf(x1[k0 + k + 1], W2[(k0 + k + 1) * D_HID + j], a1);
            a2 = fmaf(x1[k0 + k + 2], W2[(k0 + k + 2) * D_HID + j], a2);
            a3 = fmaf(x1[k0 + k + 3], W2[(k0 + k + 3) * D_HID + j], a3);
        }
        const float p = (a0 + a1) + (a2 + a3);
        if (hf == 1) part[j] = p;
        __syncthreads();
        if (hf == 0) {
            const float acc2 = b2[j] + p + part[j];
            const float s2 = acc2 / (1.0f + expf(-acc2));
            r = s2 * W3[j];
        }
    }
    #pragma unroll
    for (int off = 32; off > 0; off >>= 1)
        r += __shfl_down(r, off, 64);
    if (hf == 0 && (t & 63) == 0) wsum[t >> 6] = r;
    __syncthreads();
    const float ret = wsum[0] + wsum[1] + b3[0];
    __syncthreads();   // wsum/h/x1/part reusable by next call
    return ret;
}

// ---------------------------------------------------------------------------
// Fused single-dispatch kernel.
//   blocks [0, nchunk)          : consumers (chunk gather-sum + force zero)
//   blocks [nchunk, nchunk+118) : producers (MLP -> Etab; block 0 aggregates)
// Gate: producers release done[z]=MAGIC; producer 0 polls all, releases
// super=MAGIC2; consumers acquire super. All waits bounded w/ fallback.
// ---------------------------------------------------------------------------
__global__ __launch_bounds__(256, 5)
void mace_fused1_kernel(const float* __restrict__ embed,
                        const float* __restrict__ W1, const float* __restrict__ b1,
                        const float* __restrict__ W2, const float* __restrict__ b2,
                        const float* __restrict__ W3, const float* __restrict__ b3,
                        const int* __restrict__ z,
                        const int* __restrict__ batch,
                        float* __restrict__ energy,
                        float4* __restrict__ forces4,
                        float* __restrict__ EtabG,
                        unsigned int* __restrict__ done,   // [128]
                        unsigned int* __restrict__ superf, // [1]
                        int n, int B, int nf4, int nchunk) {
    __shared__ float h[D_EMB];
    __shared__ float x1[D_HID];
    __shared__ float part[D_HID];
    __shared__ float wsum[2];
    __shared__ float etab_s[NUM_EL];
    __shared__ float bins[NBINS];
    __shared__ int   base_s;
    __shared__ int   tmo_s;

    const int t   = threadIdx.x;
    const int bid = blockIdx.x;

    if (bid >= nchunk) {
        // ================= producer =================
        const int zz = bid - nchunk;

        // zero energy (blocks zz=0..3 cover B=1024)
        const int eidx = zz * 256 + t;
        if (eidx < B) energy[eidx] = 0.f;

        const float E = mlp_E(zz, t, embed, W1, b1, W2, b2, W3, b3,
                              h, x1, part, wsum);
        if (t == 0) EtabG[zz] = E;

        __threadfence();          // publish Etab[zz] + energy zeros (agent)
        __syncthreads();
        if (t == 0)
            __hip_atomic_store(&done[zz], MAGIC, __ATOMIC_RELEASE,
                               __HIP_MEMORY_SCOPE_AGENT);

        if (zz == 0) {
            // ---- aggregator ----
            if (t == 0) {
                int ok = 1;
                for (int w = 1; w < NUM_EL; ++w) {
                    int it = 0;
                    while (__hip_atomic_load(&done[w], __ATOMIC_ACQUIRE,
                                             __HIP_MEMORY_SCOPE_AGENT) != MAGIC) {
                        if (++it > ALIMIT) { ok = 0; break; }
                        __builtin_amdgcn_s_sleep(16);
                    }
                    if (!ok) break;
                }
                tmo_s = !ok;
            }
            __syncthreads();
            if (tmo_s) {
                // never expected: recompute whole table (identical values)
                for (int w = 0; w < NUM_EL; ++w) {
                    const float Ew = mlp_E(w, t, embed, W1, b1, W2, b2, W3, b3,
                                           h, x1, part, wsum);
                    if (t == 0) EtabG[w] = Ew;
                }
            }
            __threadfence();
            __syncthreads();
            if (t == 0)
                __hip_atomic_store(superf, MAGIC2, __ATOMIC_RELEASE,
                                   __HIP_MEMORY_SCOPE_AGENT);
        }
        return;
    }

    // ================= consumer =================
    const int chunk = bid * CHUNK;
    const int n4    = n >> 2;
    const int i4    = (chunk >> 2) + t;
    const bool valid = (i4 < n4);

    // issue gather loads early; values live in registers across the wait
    int4 zv = make_int4(0, 0, 0, 0), bv = make_int4(0, 0, 0, 0);
    if (valid) {
        zv = ((const int4*)z)[i4];
        bv = ((const int4*)batch)[i4];
    }
    if (t == 0) base_s = bv.x;   // batch[chunk]

    // zero forces (~3 float4 per thread), overlaps the producer MLP
    {
        const float4 z4f = make_float4(0.f, 0.f, 0.f, 0.f);
        const int stride = nchunk * 256;
        for (int i = bid * 256 + t; i < nf4; i += stride) forces4[i] = z4f;
    }

    // ---- gate on super-flag ----
    if (t == 0) {
        int it = 0, ok = 1;
        while (__hip_atomic_load(superf, __ATOMIC_ACQUIRE,
                                 __HIP_MEMORY_SCOPE_AGENT) != MAGIC2) {
            if (++it > CLIMIT) { ok = 0; break; }
            __builtin_amdgcn_s_sleep(32);
        }
        tmo_s = !ok;
    }
    __syncthreads();
    __threadfence();   // acquire side: invalidate stale lines before Etab reads

    if (tmo_s) {
        // never expected: self-compute the table (identical values)
        for (int w = 0; w < NUM_EL; ++w) {
            const float Ew = mlp_E(w, t, embed, W1, b1, W2, b2, W3, b3,
                                   h, x1, part, wsum);
            if (t == 0) etab_s[w] = Ew;
        }
    } else {
        if (t < NUM_EL) etab_s[t] = EtabG[t];
    }
    if (t < NBINS) bins[t] = 0.f;
    __syncthreads();

    const int base = base_s;
    if (valid) {
        const float e0 = etab_s[zv.x], e1 = etab_s[zv.y];
        const float e2 = etab_s[zv.z], e3 = etab_s[zv.w];
        float acc = e0;
        int   bc  = bv.x;
        #define FLUSH()                                                     \
            do {                                                            \
                const int bin = bc - base;                                  \
                if (bin < NBINS) atomicAdd(&bins[bin], acc);                \
                else             atomicAdd(&energy[bc], acc);               \
            } while (0)
        if (bv.y == bc) acc += e1; else { FLUSH(); bc = bv.y; acc = e1; }
        if (bv.z == bc) acc += e2; else { FLUSH(); bc = bv.z; acc = e2; }
        if (bv.w == bc) acc += e3; else { FLUSH(); bc = bv.w; acc = e3; }
        FLUSH();
        #undef FLUSH
    }

    // scalar-tail insurance for n % 4 != 0 (not hit at n = 1e6)
    if (bid == nchunk - 1 && t == 0) {
        for (int i = n4 << 2; i < n; ++i)
            atomicAdd(&energy[batch[i]], etab_s[z[i]]);
    }

    __syncthreads();
    if (t < NBINS) {
        const float v = bins[t];
        if (v != 0.f) atomicAdd(&energy[base + t], v);
    }
}

extern "C" void kernel_launch(void* const* d_in, const int* in_sizes, int n_in,
                              void* d_out, int out_size, void* d_ws, size_t ws_size,
                              hipStream_t stream) {
    // 0 positions, 1 embed, 2 W1, 3 b1, 4 W2, 5 b2, 6 W3, 7 b3,
    // 8 atomic_numbers, 9 batch
    const float* embed = (const float*)d_in[1];
    const float* W1    = (const float*)d_in[2];
    const float* b1    = (const float*)d_in[3];
    const float* W2    = (const float*)d_in[4];
    const float* b2    = (const float*)d_in[5];
    const float* W3    = (const float*)d_in[6];
    const float* b3    = (const float*)d_in[7];
    const int*   zp    = (const int*)d_in[8];
    const int*   batch = (const int*)d_in[9];
    const int    n     = in_sizes[8];               // 1,000,000

    const int B      = out_size - 3 * n;            // 1024
    const int nf4    = (3 * n) / 4;                 // 750,000
    const int nchunk = (n + CHUNK - 1) / CHUNK;     // 977

    float*  energy  = (float*)d_out;                 // [B]
    float4* forces4 = (float4*)((float*)d_out + B);  // [3N], 16B-aligned
    float*        Etab  = (float*)d_ws;                            // 128 floats
    unsigned int* done  = (unsigned int*)((char*)d_ws + 512);      // 128 words
    unsigned int* superf= (unsigned int*)((char*)d_ws + 1536);     // own line

    mace_fused1_kernel<<<nchunk + NUM_EL, 256, 0, stream>>>(
        embed, W1, b1, W2, b2, W3, b3, zp, batch,
        energy, forces4, Etab, done, superf, n, B, nf4, nchunk);
}

// Round 8
// 13.908 us; speedup vs baseline: 111.1859x; 111.1859x over previous
//
#include <hip/hip_runtime.h>

#define D_EMB   64
#define D_HID   128
#define NUM_EL  118
#define HPAD    120          // padded hist row (ints)
#define NSLOT   4            // molecules tracked per chunk
#define CHUNK   1024         // atoms per chunk (256 int4 / block)
#define K1_GRID 2048

// ---------------------------------------------------------------------------
// Kernel 1 ("prep"): single pass over all big data. Roles by blockIdx:
//   [0, nchunk)             : chunk blocks — read z+batch as int4, build
//                             per-chunk 4-slot x 118 LDS histogram (DS
//                             atomics), diff-pass -> starts[], write hist
//                             rows (block-owned, no global atomics)
//   [nchunk, nchunk+118)    : MLP blocks -> Etab[z]
//   all blocks              : grid-strided float4 zero of forces (12 MB)
// ---------------------------------------------------------------------------
__global__ __launch_bounds__(256)
void mace_prep_kernel(const float* __restrict__ embed,
                      const float* __restrict__ W1, const float* __restrict__ b1,
                      const float* __restrict__ W2, const float* __restrict__ b2,
                      const float* __restrict__ W3, const float* __restrict__ b3,
                      const int* __restrict__ z,
                      const int* __restrict__ batch,
                      float* __restrict__ Etab,
                      int* __restrict__ starts,
                      int* __restrict__ chunkbase,
                      int* __restrict__ hist,
                      float4* __restrict__ forces4,
                      int nf4, int n, int B, int nchunk) {
    const int t   = threadIdx.x;
    const int bid = blockIdx.x;

    // ---- force zero (all blocks) ----
    {
        const float4 z4f = make_float4(0.f, 0.f, 0.f, 0.f);
        for (int i = bid * 256 + t; i < nf4; i += K1_GRID * 256)
            forces4[i] = z4f;
    }

    if (bid < nchunk) {
        // ================= chunk block =================
        __shared__ unsigned int shist[NSLOT * HPAD];
        __shared__ int base_s;

        for (int i = t; i < NSLOT * HPAD; i += 256) shist[i] = 0u;

        const int n4 = n >> 2;
        const int i4 = (bid << 8) + t;          // 256 int4 per chunk
        const bool valid = (i4 < n4);
        int4 zv = make_int4(0,0,0,0), bv = make_int4(0,0,0,0);
        if (valid) {
            zv = ((const int4*)z)[i4];
            bv = ((const int4*)batch)[i4];
        }
        if (t == 0) base_s = bv.x;              // first atom of chunk
        __syncthreads();
        const int base = base_s;

        if (valid) {
            // histogram (batch sorted => bv.* - base >= 0)
            const int s0 = bv.x - base, s1 = bv.y - base;
            const int s2 = bv.z - base, s3 = bv.w - base;
            if (s0 < NSLOT) atomicAdd(&shist[s0 * HPAD + zv.x], 1u);
            if (s1 < NSLOT) atomicAdd(&shist[s1 * HPAD + zv.y], 1u);
            if (s2 < NSLOT) atomicAdd(&shist[s2 * HPAD + zv.z], 1u);
            if (s3 < NSLOT) atomicAdd(&shist[s3 * HPAD + zv.w], 1u);

            // diff-pass -> starts
            const int idx = i4 << 2;
            if (bv.x != bv.y) { for (int b = bv.x + 1; b <= bv.y; ++b) starts[b] = idx + 1; }
            if (bv.y != bv.z) { for (int b = bv.y + 1; b <= bv.z; ++b) starts[b] = idx + 2; }
            if (bv.z != bv.w) { for (int b = bv.z + 1; b <= bv.w; ++b) starts[b] = idx + 3; }
            if (idx + 4 < n) {
                const int nx = batch[idx + 4];
                if (bv.w != nx) { for (int b = bv.w + 1; b <= nx; ++b) starts[b] = idx + 4; }
            }
        }
        if (t == 0) {
            chunkbase[bid] = base;
            if (bid == 0) {
                const int first = batch[0], last = batch[n - 1];
                for (int b = 0; b <= first; ++b) starts[b] = 0;
                for (int b = last + 1; b <= B; ++b) starts[b] = n;
            }
        }
        __syncthreads();

        // flush hist rows (block-owned, plain coalesced stores)
        int* __restrict__ hrow = hist + (size_t)bid * (NSLOT * HPAD);
        for (int i = t; i < NSLOT * HPAD; i += 256) hrow[i] = (int)shist[i];

    } else if (bid < nchunk + NUM_EL) {
        // ================= MLP block =================
        __shared__ float h[D_EMB];
        __shared__ float x1[D_HID];
        __shared__ float part[D_HID];
        __shared__ float wsum[2];
        const int zz = bid - nchunk;
        const int j  = t & 127;
        const int hf = t >> 7;

        if (t < D_EMB) h[t] = embed[zz * D_EMB + t];
        __syncthreads();

        // layer 1 (k split 32/32 across hf)
        {
            const int k0 = hf * 32;
            float a0 = 0.f, a1 = 0.f, a2 = 0.f, a3 = 0.f;
            #pragma unroll
            for (int k = 0; k < 32; k += 4) {
                a0 = fmaf(h[k0 + k + 0], W1[(k0 + k + 0) * D_HID + j], a0);
                a1 = fmaf(h[k0 + k + 1], W1[(k0 + k + 1) * D_HID + j], a1);
                a2 = fmaf(h[k0 + k + 2], W1[(k0 + k + 2) * D_HID + j], a2);
                a3 = fmaf(h[k0 + k + 3], W1[(k0 + k + 3) * D_HID + j], a3);
            }
            const float p = (a0 + a1) + (a2 + a3);
            if (hf == 1) part[j] = p;
            __syncthreads();
            if (hf == 0) {
                const float acc = b1[j] + p + part[j];
                x1[j] = acc / (1.0f + expf(-acc));
            }
            __syncthreads();
        }
        // layer 2 + dot(W3) (k split 64/64 across hf)
        float r = 0.f;
        {
            const int k0 = hf * 64;
            float a0 = 0.f, a1 = 0.f, a2 = 0.f, a3 = 0.f;
            #pragma unroll
            for (int k = 0; k < 64; k += 4) {
                a0 = fmaf(x1[k0 + k + 0], W2[(k0 + k + 0) * D_HID + j], a0);
                a1 = fmaf(x1[k0 + k + 1], W2[(k0 + k + 1) * D_HID + j], a1);
                a2 = fmaf(x1[k0 + k + 2], W2[(k0 + k + 2) * D_HID + j], a2);
                a3 = fmaf(x1[k0 + k + 3], W2[(k0 + k + 3) * D_HID + j], a3);
            }
            const float p = (a0 + a1) + (a2 + a3);
            if (hf == 1) part[j] = p;
            __syncthreads();
            if (hf == 0) {
                const float acc2 = b2[j] + p + part[j];
                const float s2 = acc2 / (1.0f + expf(-acc2));
                r = s2 * W3[j];
            }
        }
        #pragma unroll
        for (int off = 32; off > 0; off >>= 1)
            r += __shfl_down(r, off, 64);
        if (hf == 0 && (t & 63) == 0) wsum[t >> 6] = r;
        __syncthreads();
        if (t == 0) Etab[zz] = wsum[0] + wsum[1] + b3[0];
    }
}

// ---------------------------------------------------------------------------
// Kernel 2: one block per molecule. energy[b] = sum_c dot(hist[c][b-base], E)
// over the 1-2 chunks overlapping molecule b. Slot overflow (impossible for
// this data, guarded anyway) falls back to raw z reads. Direct store.
// ---------------------------------------------------------------------------
__global__ __launch_bounds__(256)
void mace_energy_kernel(const int* __restrict__ z,
                        const int* __restrict__ starts,
                        const int* __restrict__ chunkbase,
                        const int* __restrict__ hist,
                        const float* __restrict__ EtabG,
                        float* __restrict__ energy, int n) {
    __shared__ float etab_s[NUM_EL];
    __shared__ float wsum[4];
    const int b = blockIdx.x;
    const int t = threadIdx.x;

    if (t < NUM_EL) etab_s[t] = EtabG[t];
    const int start = starts[b];
    const int end   = starts[b + 1];
    __syncthreads();

    float acc = 0.f;
    if (end > start) {
        const int c0 = start >> 10;
        const int c1 = (end - 1) >> 10;
        for (int c = c0; c <= c1; ++c) {
            const int slot = b - chunkbase[c];
            if (slot < NSLOT) {
                if (t < NUM_EL) {
                    const int cnt = hist[((size_t)c * NSLOT + slot) * HPAD + t];
                    acc = fmaf((float)cnt, etab_s[t], acc);
                }
            } else {
                // overflow fallback: read raw z for the intersection
                const int lo = max(start, c << 10);
                const int hi = min(end, (c + 1) << 10);
                for (int i = lo + t; i < hi; i += 256)
                    acc += etab_s[z[i]];
            }
        }
    }

    #pragma unroll
    for (int off = 32; off > 0; off >>= 1)
        acc += __shfl_down(acc, off, 64);
    if ((t & 63) == 0) wsum[t >> 6] = acc;
    __syncthreads();
    if (t == 0) energy[b] = (wsum[0] + wsum[1]) + (wsum[2] + wsum[3]);
}

extern "C" void kernel_launch(void* const* d_in, const int* in_sizes, int n_in,
                              void* d_out, int out_size, void* d_ws, size_t ws_size,
                              hipStream_t stream) {
    // 0 positions, 1 embed, 2 W1, 3 b1, 4 W2, 5 b2, 6 W3, 7 b3,
    // 8 atomic_numbers, 9 batch
    const float* embed = (const float*)d_in[1];
    const float* W1    = (const float*)d_in[2];
    const float* b1    = (const float*)d_in[3];
    const float* W2    = (const float*)d_in[4];
    const float* b2    = (const float*)d_in[5];
    const float* W3    = (const float*)d_in[6];
    const float* b3    = (const float*)d_in[7];
    const int*   zp    = (const int*)d_in[8];
    const int*   batch = (const int*)d_in[9];
    const int    n     = in_sizes[8];                  // 1,000,000

    const int B      = out_size - 3 * n;               // 1024
    const int nf4    = (3 * n) / 4;                    // 750,000
    const int nchunk = (n + CHUNK - 1) / CHUNK;        // 977

    float*  energy  = (float*)d_out;                   // [B]
    float4* forces4 = (float4*)((float*)d_out + B);    // [3N], 16B-aligned

    char* ws = (char*)d_ws;
    float* Etab      = (float*)(ws);                   // 128 f32
    int*   starts    = (int*)(ws + 512);               // B+1 ints
    int*   chunkbase = (int*)(ws + 8192);              // nchunk ints
    int*   hist      = (int*)(ws + 16384);             // nchunk*4*120 ints (~1.9 MB)

    mace_prep_kernel<<<K1_GRID, 256, 0, stream>>>(embed, W1, b1, W2, b2, W3, b3,
                                                  zp, batch, Etab, starts,
                                                  chunkbase, hist, forces4,
                                                  nf4, n, B, nchunk);
    mace_energy_kernel<<<B, 256, 0, stream>>>(zp, starts, chunkbase, hist,
                                              Etab, energy, n);
}